// Round 12
// baseline (688.719 us; speedup 1.0000x reference)
//
#include <hip/hip_runtime.h>
#include <hip/hip_cooperative_groups.h>
#include <math.h>

namespace cg = cooperative_groups;

#define N_NODES 50000
#define E_EDGES 250000
#define HD 256          // H * D per edge type
#define NH 4
#define DH 64
#define NC 153
#define KDIM 256        // all GEMMs have K = 256
#define HD2 512         // both edge types concatenated
#define SLOTS 64        // per-(node,etype) LDS score/src stash (mean degree 5)
#define CSR_GRID 512    // cooperative grid: 2 blocks/CU, guaranteed co-resident

// ---------- fp32 <-> bf16 ----------
__device__ __forceinline__ unsigned short f2bf(float f) {
    unsigned u = __float_as_uint(f);
    u = u + 0x7FFFu + ((u >> 16) & 1u);
    return (unsigned short)(u >> 16);
}
__device__ __forceinline__ float bf2f(unsigned short b) {
    return __uint_as_float(((unsigned)b) << 16);
}

typedef __attribute__((ext_vector_type(8))) short bf16x8;
typedef __attribute__((ext_vector_type(4))) float f32x4;

// ================= K=256 bf16 MFMA GEMM (unchanged from r11) =================
template<int NCB, bool SCORES>
__global__ __launch_bounds__(256, 4) void gemm_k256(
        const unsigned short* __restrict__ A, const unsigned short* __restrict__ BT,
        float* __restrict__ Cf, unsigned short* __restrict__ Cbf,
        const float* __restrict__ bias,
        const float* __restrict__ as_a, const float* __restrict__ ad_a,
        const float* __restrict__ as_b, const float* __restrict__ ad_b,
        float* __restrict__ ssrc8, float* __restrict__ sdst8,
        int M, int Ncols) {
    __shared__ unsigned short Bs[64 * 256];   // 32 KB: B tile, then C-transpose buf
    const int tid = threadIdx.x;
    const int lane = tid & 63;
    const int wave = tid >> 6;
    const int quad = lane >> 4;
    const int l16 = lane & 15;

    // ---- bijective XCD swizzle: dispatch wg -> logical (col-minor) ----
    const int nwg = gridDim.x;
    const int wg = blockIdx.x;
    const int x = wg & 7, ii = wg >> 3;
    const int q = nwg >> 3, r = nwg & 7;
    const int logical = (x < r ? x * (q + 1) : r * (q + 1) + (x - r) * q) + ii;
    const int cb = logical % NCB;
    const int rb = logical / NCB;
    const int row0 = rb * 128 + wave * 32;
    const int col0 = cb * 64;

    // ---- stage B(col0..col0+63, 0..255) -> LDS with XOR swizzle ----
    #pragma unroll
    for (int j = 0; j < 8; j++) {
        const int c = tid + 256 * j;         // 16B chunk id (2048 total)
        const int rr = c >> 5;               // B row (0..63)
        const int kb = (c & 31) << 4;        // byte offset within 512B row
        const uint4 v = *(const uint4*)((const char*)BT +
                            (size_t)(col0 + rr) * 512 + kb);
        *(uint4*)((char*)Bs + rr * 512 + (kb ^ ((rr & 7) << 4))) = v;
    }
    __syncthreads();

    f32x4 acc[2][4];
    #pragma unroll
    for (int i = 0; i < 2; i++)
        #pragma unroll
        for (int j = 0; j < 4; j++) acc[i][j] = (f32x4)0.f;

    size_t a_off[2];
    #pragma unroll
    for (int mt = 0; mt < 2; mt++) {
        int gr = row0 + mt * 16 + l16;
        if (gr >= M) gr = M - 1;
        a_off[mt] = (size_t)gr * KDIM + quad * 8;
    }
    const char* Bsc = (const char*)Bs;
    const int bbase = l16 * 512 + ((quad * 16) ^ ((l16 & 7) << 4));

    bf16x8 a_buf[4][2];    // ring-4 A prefetch (32 VGPR at mt=2)
    bf16x8 b_cur[4], b_nxt[4];
    #pragma unroll
    for (int s = 0; s < 3; s++)
        #pragma unroll
        for (int mt = 0; mt < 2; mt++)
            a_buf[s][mt] = *(const bf16x8*)&A[a_off[mt] + s * 32];
    #pragma unroll
    for (int nt = 0; nt < 4; nt++)
        b_cur[nt] = *(const bf16x8*)(Bsc + nt * 16 * 512 + bbase);

    #pragma unroll
    for (int kk = 0; kk < 8; kk++) {
        if (kk + 3 < 8) {
            #pragma unroll
            for (int mt = 0; mt < 2; mt++)
                a_buf[(kk + 3) & 3][mt] =
                    *(const bf16x8*)&A[a_off[mt] + (kk + 3) * 32];
        }
        if (kk < 7) {
            #pragma unroll
            for (int nt = 0; nt < 4; nt++)
                b_nxt[nt] = *(const bf16x8*)(Bsc + nt * 16 * 512 +
                                (bbase ^ ((kk + 1) * 64)));
        }
        #pragma unroll
        for (int mt = 0; mt < 2; mt++)
            #pragma unroll
            for (int nt = 0; nt < 4; nt++)
                acc[mt][nt] = __builtin_amdgcn_mfma_f32_16x16x32_bf16(
                                  a_buf[kk & 3][mt], b_cur[nt], acc[mt][nt], 0, 0, 0);
        #pragma unroll
        for (int nt = 0; nt < 4; nt++) b_cur[nt] = b_nxt[nt];
    }

    if constexpr (SCORES) {
        // ---- fused attention scores: this col-block == (etype cb>>2, head cb&3)
        const float* as_p = (cb < 4) ? as_a : as_b;
        const float* ad_p = (cb < 4) ? ad_a : ad_b;
        const int hd = (cb & 3) * 64;
        float asv[4], adv[4];
        #pragma unroll
        for (int nt = 0; nt < 4; nt++) {
            asv[nt] = as_p[hd + nt * 16 + l16];
            adv[nt] = ad_p[hd + nt * 16 + l16];
        }
        #pragma unroll
        for (int mt = 0; mt < 2; mt++) {
            #pragma unroll
            for (int rr = 0; rr < 4; rr++) {
                float ps = acc[mt][0][rr] * asv[0] + acc[mt][1][rr] * asv[1]
                         + acc[mt][2][rr] * asv[2] + acc[mt][3][rr] * asv[3];
                float pd = acc[mt][0][rr] * adv[0] + acc[mt][1][rr] * adv[1]
                         + acc[mt][2][rr] * adv[2] + acc[mt][3][rr] * adv[3];
                #pragma unroll
                for (int off = 1; off < 16; off <<= 1) {
                    ps += __shfl_xor(ps, off);
                    pd += __shfl_xor(pd, off);
                }
                const int m = row0 + mt * 16 + quad * 4 + rr;
                if (l16 == 0 && m < M) {
                    ssrc8[m * 8 + cb] = ps;
                    sdst8[m * 8 + cb] = pd;
                }
            }
        }

        // ---- C write via LDS transpose: 4 dwordx4 stores/thread ----
        __syncthreads();                      // Bs (B tile) no longer needed
        char* myC = (char*)Bs + wave * 4096;  // 32 rows x 64 cols bf16 = 4KB/wave
        #pragma unroll
        for (int mt = 0; mt < 2; mt++)
            #pragma unroll
            for (int nt = 0; nt < 4; nt++)
                #pragma unroll
                for (int rr = 0; rr < 4; rr++)
                    *(unsigned short*)(myC + (mt * 16 + quad * 4 + rr) * 128 +
                                       (nt * 16 + l16) * 2) = f2bf(acc[mt][nt][rr]);
        #pragma unroll
        for (int it = 0; it < 4; it++) {
            const int chunk = it * 64 + lane;
            const int lr = chunk >> 3;            // local row (0..31)
            const int cbyte = (chunk & 7) * 16;   // byte offset within 128B row
            const uint4 v = *(const uint4*)(myC + lr * 128 + cbyte);
            const int m = row0 + lr;
            if (m < M)
                *(uint4*)((char*)Cbf + ((size_t)m * Ncols + col0) * 2 + cbyte) = v;
        }
    } else {
        #pragma unroll
        for (int mt = 0; mt < 2; mt++) {
            #pragma unroll
            for (int nt = 0; nt < 4; nt++) {
                const int n = col0 + nt * 16 + l16;
                if (n >= Ncols) continue;
                const float bv = bias ? bias[n] : 0.f;
                #pragma unroll
                for (int rr = 0; rr < 4; rr++) {
                    const int m = row0 + mt * 16 + quad * 4 + rr;
                    if (m < M) Cf[(size_t)m * Ncols + n] = acc[mt][nt][rr] + bv;
                }
            }
        }
    }
}

// ---------- fp32 -> bf16 conversion (vectorized) ----------
__global__ __launch_bounds__(256) void convert_bf16_kernel(
        const float* __restrict__ in, unsigned short* __restrict__ out, int n) {
    const int i = (blockIdx.x * 256 + threadIdx.x) * 4;
    if (i + 3 < n) {
        const float4 v = *(const float4*)&in[i];
        ushort4 o;
        o.x = f2bf(v.x); o.y = f2bf(v.y); o.z = f2bf(v.z); o.w = f2bf(v.w);
        *(ushort4*)&out[i] = o;
    } else {
        for (int j = i; j < n; j++) out[j] = f2bf(in[j]);
    }
}

// ---------- dual weight transpose+convert: Wa,Wb[K,256] -> Wt[512,K] bf16 ----------
__global__ __launch_bounds__(256) void wt2_kernel(
        const float* __restrict__ Wa, const float* __restrict__ Wb,
        unsigned short* __restrict__ Wt) {
    const int idx = blockIdx.x * 256 + threadIdx.x;
    const int n = idx >> 8, k = idx & 255;
    Wt[idx] = (n < HD) ? f2bf(Wa[(size_t)k * HD + n])
                       : f2bf(Wb[(size_t)k * HD + (n - HD)]);
}

// ---------- single weight transpose+convert with zero-pad ----------
__global__ __launch_bounds__(256) void wt_kernel(
        const float* __restrict__ W, unsigned short* __restrict__ Wt, int Nc) {
    const int idx = blockIdx.x * 256 + threadIdx.x;
    const int n = idx >> 8, k = idx & 255;
    Wt[idx] = (n < Nc) ? f2bf(W[(size_t)k * Nc + n]) : (unsigned short)0;
}

// ========== cooperative CSR build: zero+hist+scan+scan+add+scatter in ONE ==========
// r11 used 6 kernels with 5 full drain/launch cycles between them; this fuses the
// pipeline with grid.sync() (hipLaunchCooperativeKernel, harness-supported) and
// keeps deg/excl L2-hot. Chunk size 256 (was 1024): offsets indexed by i>>8.
// All phases grid-stride -> correctness independent of grid size; CSR_GRID=512
// (2 blocks/CU) guarantees co-residency.
__global__ __launch_bounds__(256) void csr_build_coop(
        const int* __restrict__ ei_a, const int* __restrict__ ei_b,
        int* __restrict__ deg, int* __restrict__ cursor,
        int* __restrict__ rp_a, int* __restrict__ cs_a,
        int* __restrict__ rp_b, int* __restrict__ cs_b,
        int* __restrict__ excl, int* __restrict__ bsums) {
    cg::grid_group grid = cg::this_grid();
    const int nt = gridDim.x * 256;
    const int gt = blockIdx.x * 256 + threadIdx.x;
    const int lane = threadIdx.x & 63;
    const int wid  = threadIdx.x >> 6;
    const int n2 = 2 * N_NODES;
    const int e2 = 2 * E_EDGES;
    const int nchunks = (n2 + 255) / 256;     // 391

    // phase 1: zero degree table
    for (int i = gt; i < n2; i += nt) deg[i] = 0;
    grid.sync();

    // phase 2: histogram (dst degrees, both etypes concatenated)
    for (int t = gt; t < e2; t += nt) {
        if (t < E_EDGES) atomicAdd(&deg[ei_a[E_EDGES + t]], 1);
        else             atomicAdd(&deg[N_NODES + ei_b[t]], 1);  // ei_b[t]=dst row
    }
    grid.sync();

    // phase 3: per-256-chunk exclusive scan -> excl, chunk totals -> bsums
    __shared__ int wsum[4];
    for (int c = blockIdx.x; c < nchunks; c += gridDim.x) {
        const int i = c * 256 + threadIdx.x;
        const int v = (i < n2) ? deg[i] : 0;
        int s = v;
        #pragma unroll
        for (int off = 1; off < 64; off <<= 1) {
            const int t = __shfl_up(s, off);
            if (lane >= off) s += t;
        }
        if (lane == 63) wsum[wid] = s;
        __syncthreads();
        int woff = 0;
        #pragma unroll
        for (int w = 0; w < 3; w++) if (w < wid) woff += wsum[w];
        if (i < n2) excl[i] = s - v + woff;
        if (threadIdx.x == 0)
            bsums[c] = wsum[0] + wsum[1] + wsum[2] + wsum[3];
        __syncthreads();     // wsum reuse guard (only matters if multi-iter)
    }
    grid.sync();

    // phase 4: exclusive scan of 391 chunk totals (block 0, one wave, carry loop)
    if (blockIdx.x == 0 && threadIdx.x < 64) {
        int carry = 0;
        for (int base = 0; base < nchunks; base += 64) {
            const int idx = base + lane;
            const int v = (idx < nchunks) ? bsums[idx] : 0;
            int s = v;
            #pragma unroll
            for (int off = 1; off < 64; off <<= 1) {
                const int t = __shfl_up(s, off);
                if (lane >= off) s += t;
            }
            if (idx < nchunks) bsums[idx] = carry + s - v;
            carry += __shfl(s, 63);
        }
    }
    grid.sync();

    // phase 5: global offsets -> rp / cursor
    for (int i = gt; i < n2; i += nt) {
        const int v = excl[i] + bsums[i >> 8];
        if (i < N_NODES) { rp_a[i] = v; cursor[i] = v; }
        else { const int w = v - E_EDGES; rp_b[i - N_NODES] = w; cursor[i] = w; }
    }
    if (gt == 0) { rp_a[N_NODES] = E_EDGES; rp_b[N_NODES] = E_EDGES; }
    grid.sync();

    // phase 6: scatter srcs into CSR order
    for (int t = gt; t < e2; t += nt) {
        if (t < E_EDGES) {
            const int src = ei_a[t], dst = ei_a[E_EDGES + t];
            cs_a[atomicAdd(&cursor[dst], 1)] = src;
        } else {
            const int src = ei_b[t - E_EDGES], dst = ei_b[t];
            cs_b[atomicAdd(&cursor[N_NODES + dst], 1)] = src;
        }
    }
}

// ---------- fused softmax + aggregation + epilogue; wave per node ----------
// r11 structure (max-only pass 1, LDS stash, z alongside t in pass 2) with a
// PREDICATED TAIL: at mean degree 5 the serial 1-edge tail was ~25% of pass-2
// iterations with zero memory-level parallelism. Now every group is 4-wide with
// clamped slots + zeroed p (masks wave-uniform -> no divergence); the rare
// sl+3>=SLOTS case keeps the serial global-recompute fallback.
__global__ __launch_bounds__(256) void aggregate_both_kernel(
        const int* __restrict__ rp_a, const int* __restrict__ cs_a,
        const int* __restrict__ rp_b, const int* __restrict__ cs_b,
        const unsigned short* __restrict__ h_ab,
        const float* __restrict__ ssrc8, const float* __restrict__ sdst8,
        const float* __restrict__ b1, const float* __restrict__ b2,
        unsigned short* __restrict__ out_bf, int do_leaky) {
    __shared__ float s_lds[4][2][NH][SLOTS];   // 8 KB: post-leaky scores
    __shared__ int   src_lds[4][2][SLOTS];     // 2 KB: source indices
    const int wv = threadIdx.x >> 6;
    const int node = blockIdx.x * 4 + wv;
    const int lane = threadIdx.x & 63;
    if (node >= N_NODES) return;
    const int hh = lane >> 4;
    const int l16 = lane & 15;
    const int c4 = lane * 4;

    float4 a = make_float4(0.f, 0.f, 0.f, 0.f);

    #pragma unroll
    for (int et = 0; et < 2; et++) {
        const int* rp = et ? rp_b : rp_a;
        const int* cs = et ? cs_b : cs_a;
        const size_t hoff = et ? (size_t)HD : 0;
        const int r8 = et * 4 + hh;
        const float sdv = sdst8[node * 8 + r8];
        const int beg = rp[node], end = rp[node + 1];
        float* sld = &s_lds[wv][et][hh][0];
        int*   srl = &src_lds[wv][et][0];

        // ---- pass 1: MAX only; stash src + post-leaky score in LDS ----
        float mm = -INFINITY;
        for (int c = beg; c < end; c += 16) {
            const int e = c + l16;
            float s = -INFINITY;
            if (e < end) {
                const int srci = cs[e];
                s = ssrc8[srci * 8 + r8] + sdv;
                s = (s >= 0.f) ? s : 0.2f * s;
                const int sl = e - beg;
                if (sl < SLOTS) {
                    sld[sl] = s;
                    if (hh == 0) srl[sl] = srci;
                }
            }
            #pragma unroll
            for (int off = 1; off < 16; off <<= 1)
                s = fmaxf(s, __shfl_xor(s, off));
            mm = fmaxf(mm, s);
        }

        // ---- pass 2: predicated 4-wide gather + weighted sum + z ----
        float4 t = make_float4(0.f, 0.f, 0.f, 0.f);
        float z = 0.f;
        for (int e0 = beg; e0 < end; e0 += 4) {
            const int sl = e0 - beg;         // wave-uniform, multiple of 4
            if (sl + 3 < SLOTS) {
                const bool m1 = (e0 + 1 < end);
                const bool m2 = (e0 + 2 < end);
                const bool m3 = (e0 + 3 < end);
                const int4 sv = *(const int4*)&srl[sl];
                const float4 sc = *(const float4*)&sld[sl];
                const int s0 = sv.x;
                const int s1 = m1 ? sv.y : s0;
                const int s2 = m2 ? sv.z : s0;
                const int s3 = m3 ? sv.w : s0;
                const float p0 = __expf(sc.x - mm);
                const float p1 = m1 ? __expf(sc.y - mm) : 0.f;
                const float p2 = m2 ? __expf(sc.z - mm) : 0.f;
                const float p3 = m3 ? __expf(sc.w - mm) : 0.f;
                z += (p0 + p1) + (p2 + p3);
                const ushort4 h0 = *(const ushort4*)&h_ab[(size_t)s0 * HD2 + hoff + c4];
                const ushort4 h1 = *(const ushort4*)&h_ab[(size_t)s1 * HD2 + hoff + c4];
                const ushort4 h2 = *(const ushort4*)&h_ab[(size_t)s2 * HD2 + hoff + c4];
                const ushort4 h3 = *(const ushort4*)&h_ab[(size_t)s3 * HD2 + hoff + c4];
                t.x = fmaf(p0, bf2f(h0.x), t.x); t.y = fmaf(p0, bf2f(h0.y), t.y);
                t.z = fmaf(p0, bf2f(h0.z), t.z); t.w = fmaf(p0, bf2f(h0.w), t.w);
                t.x = fmaf(p1, bf2f(h1.x), t.x); t.y = fmaf(p1, bf2f(h1.y), t.y);
                t.z = fmaf(p1, bf2f(h1.z), t.z); t.w = fmaf(p1, bf2f(h1.w), t.w);
                t.x = fmaf(p2, bf2f(h2.x), t.x); t.y = fmaf(p2, bf2f(h2.y), t.y);
                t.z = fmaf(p2, bf2f(h2.z), t.z); t.w = fmaf(p2, bf2f(h2.w), t.w);
                t.x = fmaf(p3, bf2f(h3.x), t.x); t.y = fmaf(p3, bf2f(h3.y), t.y);
                t.z = fmaf(p3, bf2f(h3.z), t.z); t.w = fmaf(p3, bf2f(h3.w), t.w);
            } else {
                // deep-degree fallback: serial, global recompute (correct for any deg)
                const int eend = (e0 + 4 < end) ? e0 + 4 : end;
                for (int e = e0; e < eend; e++) {
                    const int src = cs[e];
                    float v0 = ssrc8[src * 8 + r8] + sdv;
                    v0 = (v0 >= 0.f) ? v0 : 0.2f * v0;
                    const float p = __expf(v0 - mm);
                    z += p;
                    const ushort4 hv =
                        *(const ushort4*)&h_ab[(size_t)src * HD2 + hoff + c4];
                    t.x = fmaf(p, bf2f(hv.x), t.x);
                    t.y = fmaf(p, bf2f(hv.y), t.y);
                    t.z = fmaf(p, bf2f(hv.z), t.z);
                    t.w = fmaf(p, bf2f(hv.w), t.w);
                }
            }
        }

        const float zz = 1.f / (z + 1e-16f);
        a.x = fmaf(t.x, zz, a.x);
        a.y = fmaf(t.y, zz, a.y);
        a.z = fmaf(t.z, zz, a.z);
        a.w = fmaf(t.w, zz, a.w);
    }

    const float4 bv1 = *(const float4*)&b1[c4];
    const float4 bv2 = *(const float4*)&b2[c4];
    float4 v;
    v.x = a.x + bv1.x + bv2.x;
    v.y = a.y + bv1.y + bv2.y;
    v.z = a.z + bv1.z + bv2.z;
    v.w = a.w + bv1.w + bv2.w;
    if (do_leaky) {
        v.x = (v.x >= 0.f) ? v.x : 0.01f * v.x;
        v.y = (v.y >= 0.f) ? v.y : 0.01f * v.y;
        v.z = (v.z >= 0.f) ? v.z : 0.01f * v.z;
        v.w = (v.w >= 0.f) ? v.w : 0.01f * v.w;
    }
    ushort4 o;
    o.x = f2bf(v.x); o.y = f2bf(v.y); o.z = f2bf(v.z); o.w = f2bf(v.w);
    *(ushort4*)&out_bf[(size_t)node * HD + c4] = o;
}

// ---------- host side ----------
#define N_ROWBLK128 ((N_NODES + 127) / 128)

static void run_layer(const unsigned short* a_bf,
                      const int* rp_a, const int* cs_a,
                      const int* rp_b, const int* cs_b,
                      const float* Wa, const float* Wb,
                      const float* as_a, const float* ad_a,
                      const float* as_b, const float* ad_b,
                      const float* b1, const float* b2,
                      unsigned short* Wt2, unsigned short* h_ab,
                      float* ssrc8, float* sdst8,
                      unsigned short* out_bf, int do_leaky,
                      hipStream_t stream) {
    wt2_kernel<<<HD2, 256, 0, stream>>>(Wa, Wb, Wt2);
    gemm_k256<8, true><<<N_ROWBLK128 * 8, 256, 0, stream>>>(
        a_bf, Wt2, nullptr, h_ab, nullptr,
        as_a, ad_a, as_b, ad_b, ssrc8, sdst8, N_NODES, HD2);
    aggregate_both_kernel<<<(N_NODES + 3) / 4, 256, 0, stream>>>(
        rp_a, cs_a, rp_b, cs_b, h_ab, ssrc8, sdst8,
        b1, b2, out_bf, do_leaky);
}

extern "C" void kernel_launch(void* const* d_in, const int* in_sizes, int n_in,
                              void* d_out, int out_size, void* d_ws, size_t ws_size,
                              hipStream_t stream) {
    const float* x    = (const float*)d_in[0];
    const int*   ei_a = (const int*)d_in[1];
    const int*   ei_b = (const int*)d_in[2];
    const float* W0a = (const float*)d_in[3];
    const float* as0a = (const float*)d_in[4];
    const float* ad0a = (const float*)d_in[5];
    const float* b0a = (const float*)d_in[6];
    const float* W0b = (const float*)d_in[7];
    const float* as0b = (const float*)d_in[8];
    const float* ad0b = (const float*)d_in[9];
    const float* b0b = (const float*)d_in[10];
    const float* W1a = (const float*)d_in[11];
    const float* as1a = (const float*)d_in[12];
    const float* ad1a = (const float*)d_in[13];
    const float* b1a = (const float*)d_in[14];
    const float* W1b = (const float*)d_in[15];
    const float* as1b = (const float*)d_in[16];
    const float* ad1b = (const float*)d_in[17];
    const float* b1b = (const float*)d_in[18];
    const float* Wout = (const float*)d_in[19];
    const float* bout = (const float*)d_in[20];
    float* out = (float*)d_out;

    // workspace carve
    unsigned short* h_ab  = (unsigned short*)d_ws;          // N*512 ushort
    unsigned short* bf_in = h_ab + (size_t)N_NODES * HD2;   // N*256 ushort
    unsigned short* Wt2   = bf_in + (size_t)N_NODES * HD;   // 512*256 ushort
    float* ssrc8  = (float*)(Wt2 + (size_t)HD2 * KDIM);     // N*8
    float* sdst8  = ssrc8 + (size_t)N_NODES * 8;            // N*8
    int*   ibase  = (int*)(sdst8 + (size_t)N_NODES * 8);
    int* deg     = ibase;                  // 2N (concat a|b)
    int* cursor  = deg + 2 * N_NODES;      // 2N
    int* rp_a    = cursor + 2 * N_NODES;   // N+1
    int* cs_a    = rp_a + N_NODES + 1;     // E
    int* rp_b    = cs_a + E_EDGES;         // N+1
    int* cs_b    = rp_b + N_NODES + 1;     // E
    int* excl    = cs_b + E_EDGES;         // 2N
    int* bsums   = excl + 2 * N_NODES;     // 512 (391 chunks of 256)

    const size_t NF = (size_t)N_NODES * HD;
    const int nf4_blocks = (int)((NF / 4 + 255) / 256);

    // ---- CSR for both edge types: single cooperative kernel ----
    {
        void* args[] = {
            (void*)&ei_a, (void*)&ei_b, (void*)&deg, (void*)&cursor,
            (void*)&rp_a, (void*)&cs_a, (void*)&rp_b, (void*)&cs_b,
            (void*)&excl, (void*)&bsums
        };
        hipLaunchCooperativeKernel((const void*)csr_build_coop,
                                   dim3(CSR_GRID), dim3(256), args, 0, stream);
    }

    // ---- layer 0 ----
    convert_bf16_kernel<<<nf4_blocks, 256, 0, stream>>>(x, bf_in, (int)NF);
    run_layer(bf_in, rp_a, cs_a, rp_b, cs_b, W0a, W0b,
              as0a, ad0a, as0b, ad0b, b0a, b0b, Wt2, h_ab,
              ssrc8, sdst8, bf_in, /*leaky=*/1, stream);

    // ---- layer 1 ----
    run_layer(bf_in, rp_a, cs_a, rp_b, cs_b, W1a, W1b,
              as1a, ad1a, as1b, ad1b, b1a, b1b, Wt2, h_ab,
              ssrc8, sdst8, bf_in, /*leaky=*/0, stream);

    // ---- output projection (3 x 64 padded cols covers NC=153) ----
    wt_kernel<<<KDIM, 256, 0, stream>>>(Wout, Wt2, NC);
    gemm_k256<3, false><<<N_ROWBLK128 * 3, 256, 0, stream>>>(
        bf_in, Wt2, out, nullptr, bout,
        nullptr, nullptr, nullptr, nullptr, nullptr, nullptr, N_NODES, NC);
}

// Round 14
// 397.076 us; speedup vs baseline: 1.7345x; 1.7345x over previous
//
#include <hip/hip_runtime.h>
#include <math.h>

#define N_NODES 50000
#define E_EDGES 250000
#define HD 256          // H * D per edge type
#define NH 4
#define DH 64
#define NC 153
#define KDIM 256        // all GEMMs have K = 256
#define HD2 512         // both edge types concatenated
#define SLOTS 64        // per-(node,etype) LDS score/src stash (mean degree 5)

// ---------- fp32 <-> bf16 ----------
__device__ __forceinline__ unsigned short f2bf(float f) {
    unsigned u = __float_as_uint(f);
    u = u + 0x7FFFu + ((u >> 16) & 1u);
    return (unsigned short)(u >> 16);
}
__device__ __forceinline__ float bf2f(unsigned short b) {
    return __uint_as_float(((unsigned)b) << 16);
}

typedef __attribute__((ext_vector_type(8))) short bf16x8;
typedef __attribute__((ext_vector_type(4))) float f32x4;

// ================= K=256 bf16 MFMA GEMM =================
// C[M,Ncols] = A[M,256] @ BT[Ncols,256]^T, BT zero-padded to NCB*64 rows.
// Block: 128 rows x 64 cols; 4 waves x 32 rows each share one B tile (64x256 bf16,
// 32KB LDS, XOR-swizzled). Bijective XCD swizzle (confirmed r4: FETCH 100->15.7MB).
// mt=2 per wave -> ~112 regs <= 128-reg bucket -> 16 waves/CU (r7 confirmed).
// SCORES=true: epilogue computes s_src/s_dst dots from acc and writes C bf16 via
// LDS transpose (r5 confirmed scalar-store epilogue was the r0-r4 ~64us floor).
template<int NCB, bool SCORES>
__global__ __launch_bounds__(256, 4) void gemm_k256(
        const unsigned short* __restrict__ A, const unsigned short* __restrict__ BT,
        float* __restrict__ Cf, unsigned short* __restrict__ Cbf,
        const float* __restrict__ bias,
        const float* __restrict__ as_a, const float* __restrict__ ad_a,
        const float* __restrict__ as_b, const float* __restrict__ ad_b,
        float* __restrict__ ssrc8, float* __restrict__ sdst8,
        int M, int Ncols) {
    __shared__ unsigned short Bs[64 * 256];   // 32 KB: B tile, then C-transpose buf
    const int tid = threadIdx.x;
    const int lane = tid & 63;
    const int wave = tid >> 6;
    const int quad = lane >> 4;
    const int l16 = lane & 15;

    // ---- bijective XCD swizzle: dispatch wg -> logical (col-minor) ----
    const int nwg = gridDim.x;
    const int wg = blockIdx.x;
    const int x = wg & 7, ii = wg >> 3;
    const int q = nwg >> 3, r = nwg & 7;
    const int logical = (x < r ? x * (q + 1) : r * (q + 1) + (x - r) * q) + ii;
    const int cb = logical % NCB;
    const int rb = logical / NCB;
    const int row0 = rb * 128 + wave * 32;
    const int col0 = cb * 64;

    // ---- stage B(col0..col0+63, 0..255) -> LDS with XOR swizzle ----
    #pragma unroll
    for (int j = 0; j < 8; j++) {
        const int c = tid + 256 * j;         // 16B chunk id (2048 total)
        const int rr = c >> 5;               // B row (0..63)
        const int kb = (c & 31) << 4;        // byte offset within 512B row
        const uint4 v = *(const uint4*)((const char*)BT +
                            (size_t)(col0 + rr) * 512 + kb);
        *(uint4*)((char*)Bs + rr * 512 + (kb ^ ((rr & 7) << 4))) = v;
    }
    __syncthreads();

    f32x4 acc[2][4];
    #pragma unroll
    for (int i = 0; i < 2; i++)
        #pragma unroll
        for (int j = 0; j < 4; j++) acc[i][j] = (f32x4)0.f;

    size_t a_off[2];
    #pragma unroll
    for (int mt = 0; mt < 2; mt++) {
        int gr = row0 + mt * 16 + l16;
        if (gr >= M) gr = M - 1;
        a_off[mt] = (size_t)gr * KDIM + quad * 8;
    }
    const char* Bsc = (const char*)Bs;
    const int bbase = l16 * 512 + ((quad * 16) ^ ((l16 & 7) << 4));

    bf16x8 a_buf[4][2];    // ring-4 A prefetch (32 VGPR at mt=2)
    bf16x8 b_cur[4], b_nxt[4];
    #pragma unroll
    for (int s = 0; s < 3; s++)
        #pragma unroll
        for (int mt = 0; mt < 2; mt++)
            a_buf[s][mt] = *(const bf16x8*)&A[a_off[mt] + s * 32];
    #pragma unroll
    for (int nt = 0; nt < 4; nt++)
        b_cur[nt] = *(const bf16x8*)(Bsc + nt * 16 * 512 + bbase);

    #pragma unroll
    for (int kk = 0; kk < 8; kk++) {
        if (kk + 3 < 8) {
            #pragma unroll
            for (int mt = 0; mt < 2; mt++)
                a_buf[(kk + 3) & 3][mt] =
                    *(const bf16x8*)&A[a_off[mt] + (kk + 3) * 32];
        }
        if (kk < 7) {
            #pragma unroll
            for (int nt = 0; nt < 4; nt++)
                b_nxt[nt] = *(const bf16x8*)(Bsc + nt * 16 * 512 +
                                (bbase ^ ((kk + 1) * 64)));
        }
        #pragma unroll
        for (int mt = 0; mt < 2; mt++)
            #pragma unroll
            for (int nt = 0; nt < 4; nt++)
                acc[mt][nt] = __builtin_amdgcn_mfma_f32_16x16x32_bf16(
                                  a_buf[kk & 3][mt], b_cur[nt], acc[mt][nt], 0, 0, 0);
        #pragma unroll
        for (int nt = 0; nt < 4; nt++) b_cur[nt] = b_nxt[nt];
    }

    if constexpr (SCORES) {
        // ---- fused attention scores: this col-block == (etype cb>>2, head cb&3)
        const float* as_p = (cb < 4) ? as_a : as_b;
        const float* ad_p = (cb < 4) ? ad_a : ad_b;
        const int hd = (cb & 3) * 64;
        float asv[4], adv[4];
        #pragma unroll
        for (int nt = 0; nt < 4; nt++) {
            asv[nt] = as_p[hd + nt * 16 + l16];
            adv[nt] = ad_p[hd + nt * 16 + l16];
        }
        #pragma unroll
        for (int mt = 0; mt < 2; mt++) {
            #pragma unroll
            for (int rr = 0; rr < 4; rr++) {
                float ps = acc[mt][0][rr] * asv[0] + acc[mt][1][rr] * asv[1]
                         + acc[mt][2][rr] * asv[2] + acc[mt][3][rr] * asv[3];
                float pd = acc[mt][0][rr] * adv[0] + acc[mt][1][rr] * adv[1]
                         + acc[mt][2][rr] * adv[2] + acc[mt][3][rr] * adv[3];
                #pragma unroll
                for (int off = 1; off < 16; off <<= 1) {
                    ps += __shfl_xor(ps, off);
                    pd += __shfl_xor(pd, off);
                }
                const int m = row0 + mt * 16 + quad * 4 + rr;
                if (l16 == 0 && m < M) {
                    ssrc8[m * 8 + cb] = ps;
                    sdst8[m * 8 + cb] = pd;
                }
            }
        }

        // ---- C write via LDS transpose: 4 dwordx4 stores/thread ----
        __syncthreads();                      // Bs (B tile) no longer needed
        char* myC = (char*)Bs + wave * 4096;  // 32 rows x 64 cols bf16 = 4KB/wave
        #pragma unroll
        for (int mt = 0; mt < 2; mt++)
            #pragma unroll
            for (int nt = 0; nt < 4; nt++)
                #pragma unroll
                for (int rr = 0; rr < 4; rr++)
                    *(unsigned short*)(myC + (mt * 16 + quad * 4 + rr) * 128 +
                                       (nt * 16 + l16) * 2) = f2bf(acc[mt][nt][rr]);
        #pragma unroll
        for (int it = 0; it < 4; it++) {
            const int chunk = it * 64 + lane;
            const int lr = chunk >> 3;            // local row (0..31)
            const int cbyte = (chunk & 7) * 16;   // byte offset within 128B row
            const uint4 v = *(const uint4*)(myC + lr * 128 + cbyte);
            const int m = row0 + lr;
            if (m < M)
                *(uint4*)((char*)Cbf + ((size_t)m * Ncols + col0) * 2 + cbyte) = v;
        }
    } else {
        #pragma unroll
        for (int mt = 0; mt < 2; mt++) {
            #pragma unroll
            for (int nt = 0; nt < 4; nt++) {
                const int n = col0 + nt * 16 + l16;
                if (n >= Ncols) continue;
                const float bv = bias ? bias[n] : 0.f;
                #pragma unroll
                for (int rr = 0; rr < 4; rr++) {
                    const int m = row0 + mt * 16 + quad * 4 + rr;
                    if (m < M) Cf[(size_t)m * Ncols + n] = acc[mt][nt][rr] + bv;
                }
            }
        }
    }
}

// ---------- fp32 -> bf16 conversion (vectorized) ----------
__global__ __launch_bounds__(256) void convert_bf16_kernel(
        const float* __restrict__ in, unsigned short* __restrict__ out, int n) {
    const int i = (blockIdx.x * 256 + threadIdx.x) * 4;
    if (i + 3 < n) {
        const float4 v = *(const float4*)&in[i];
        ushort4 o;
        o.x = f2bf(v.x); o.y = f2bf(v.y); o.z = f2bf(v.z); o.w = f2bf(v.w);
        *(ushort4*)&out[i] = o;
    } else {
        for (int j = i; j < n; j++) out[j] = f2bf(in[j]);
    }
}

// ---------- dual weight transpose+convert: Wa,Wb[K,256] -> Wt[512,K] bf16 ----------
__global__ __launch_bounds__(256) void wt2_kernel(
        const float* __restrict__ Wa, const float* __restrict__ Wb,
        unsigned short* __restrict__ Wt) {
    const int idx = blockIdx.x * 256 + threadIdx.x;
    const int n = idx >> 8, k = idx & 255;
    Wt[idx] = (n < HD) ? f2bf(Wa[(size_t)k * HD + n])
                       : f2bf(Wb[(size_t)k * HD + (n - HD)]);
}

// ---------- single weight transpose+convert with zero-pad ----------
__global__ __launch_bounds__(256) void wt_kernel(
        const float* __restrict__ W, unsigned short* __restrict__ Wt, int Nc) {
    const int idx = blockIdx.x * 256 + threadIdx.x;
    const int n = idx >> 8, k = idx & 255;
    Wt[idx] = (n < Nc) ? f2bf(W[(size_t)k * Nc + n]) : (unsigned short)0;
}

// ---------- CSR construction, BOTH etypes in one pass (concatenated) ----------
// r12 LESSON: fusing these 6 kernels with grid.sync() cost 307us (grid-wide
// cooperative sync ~60us EACH on 8 non-coherent XCDs). Launch boundaries are
// 15x cheaper. Split kernels restored (r11-measured ~25us total).
__global__ __launch_bounds__(256) void zero_int_kernel(int* __restrict__ p, int n) {
    const int i = blockIdx.x * 256 + threadIdx.x;
    if (i < n) p[i] = 0;
}

__global__ __launch_bounds__(256) void hist2_kernel(
        const int* __restrict__ ei_a, const int* __restrict__ ei_b,
        int* __restrict__ deg) {
    const int t = blockIdx.x * 256 + threadIdx.x;
    if (t < E_EDGES)          atomicAdd(&deg[ei_a[E_EDGES + t]], 1);
    else if (t < 2 * E_EDGES) atomicAdd(&deg[N_NODES + ei_b[t]], 1);
}

__global__ __launch_bounds__(1024) void scan_local_kernel(
        const int* __restrict__ deg, int* __restrict__ excl,
        int* __restrict__ bsums, int n) {
    __shared__ int wsum[16];
    const int i = blockIdx.x * 1024 + threadIdx.x;
    const int lane = threadIdx.x & 63;
    const int wid = threadIdx.x >> 6;
    const int v = (i < n) ? deg[i] : 0;
    int s = v;
    #pragma unroll
    for (int off = 1; off < 64; off <<= 1) {
        const int t = __shfl_up(s, off);
        if (lane >= off) s += t;
    }
    if (lane == 63) wsum[wid] = s;
    __syncthreads();
    if (wid == 0) {
        int wv = (lane < 16) ? wsum[lane] : 0;
        #pragma unroll
        for (int off = 1; off < 16; off <<= 1) {
            const int t = __shfl_up(wv, off);
            if (lane >= off) wv += t;
        }
        if (lane < 16) wsum[lane] = wv;
    }
    __syncthreads();
    const int woff = (wid > 0) ? wsum[wid - 1] : 0;
    if (i < n) excl[i] = s - v + woff;
    if (threadIdx.x == 1023) bsums[blockIdx.x] = wsum[15];
}

// nb up to 128 (2N/1024 = 98): 2 values per lane
__global__ __launch_bounds__(64) void scan_bsums_kernel(
        int* __restrict__ bsums, int nb) {
    const int lane = threadIdx.x;
    const int b0 = (lane < nb) ? bsums[lane] : 0;
    const int b1 = (64 + lane < nb) ? bsums[64 + lane] : 0;
    int s0 = b0, s1 = b1;
    #pragma unroll
    for (int off = 1; off < 64; off <<= 1) {
        const int t0 = __shfl_up(s0, off);
        const int t1 = __shfl_up(s1, off);
        if (lane >= off) { s0 += t0; s1 += t1; }
    }
    const int tot0 = __shfl(s0, 63);
    bsums[lane] = s0 - b0;
    bsums[64 + lane] = tot0 + s1 - b1;
}

__global__ __launch_bounds__(256) void scan_add2_kernel(
        const int* __restrict__ excl, const int* __restrict__ bsums,
        int* __restrict__ rp_a, int* __restrict__ rp_b,
        int* __restrict__ cursor, int n2) {
    const int i = blockIdx.x * 256 + threadIdx.x;
    if (i >= n2) return;
    const int v = excl[i] + bsums[i >> 10];
    if (i < N_NODES) { rp_a[i] = v; cursor[i] = v; }
    else { const int w = v - E_EDGES; rp_b[i - N_NODES] = w; cursor[i] = w; }
    if (i == 0) { rp_a[N_NODES] = E_EDGES; rp_b[N_NODES] = E_EDGES; }
}

__global__ __launch_bounds__(256) void scatter2_kernel(
        const int* __restrict__ ei_a, const int* __restrict__ ei_b,
        int* __restrict__ cursor,
        int* __restrict__ cs_a, int* __restrict__ cs_b) {
    const int t = blockIdx.x * 256 + threadIdx.x;
    if (t < E_EDGES) {
        const int src = ei_a[t], dst = ei_a[E_EDGES + t];
        cs_a[atomicAdd(&cursor[dst], 1)] = src;
    } else if (t < 2 * E_EDGES) {
        const int src = ei_b[t - E_EDGES], dst = ei_b[t];
        cs_b[atomicAdd(&cursor[N_NODES + dst], 1)] = src;
    }
}

// ---------- fused softmax + aggregation + epilogue; wave per node ----------
// r11 structure (max-only pass 1, LDS stash, z alongside t in pass 2) with
// r12's PREDICATED TAIL: every pass-2 group is 4-wide with clamped slots +
// zeroed p (masks wave-uniform -> no divergence, keeps 4 gathers in flight
// even at the tail); rare deg>SLOTS keeps the serial global-recompute fallback.
__global__ __launch_bounds__(256) void aggregate_both_kernel(
        const int* __restrict__ rp_a, const int* __restrict__ cs_a,
        const int* __restrict__ rp_b, const int* __restrict__ cs_b,
        const unsigned short* __restrict__ h_ab,
        const float* __restrict__ ssrc8, const float* __restrict__ sdst8,
        const float* __restrict__ b1, const float* __restrict__ b2,
        unsigned short* __restrict__ out_bf, int do_leaky) {
    __shared__ float s_lds[4][2][NH][SLOTS];   // 8 KB: post-leaky scores
    __shared__ int   src_lds[4][2][SLOTS];     // 2 KB: source indices
    const int wv = threadIdx.x >> 6;
    const int node = blockIdx.x * 4 + wv;
    const int lane = threadIdx.x & 63;
    if (node >= N_NODES) return;
    const int hh = lane >> 4;
    const int l16 = lane & 15;
    const int c4 = lane * 4;

    float4 a = make_float4(0.f, 0.f, 0.f, 0.f);

    #pragma unroll
    for (int et = 0; et < 2; et++) {
        const int* rp = et ? rp_b : rp_a;
        const int* cs = et ? cs_b : cs_a;
        const size_t hoff = et ? (size_t)HD : 0;
        const int r8 = et * 4 + hh;
        const float sdv = sdst8[node * 8 + r8];
        const int beg = rp[node], end = rp[node + 1];
        float* sld = &s_lds[wv][et][hh][0];
        int*   srl = &src_lds[wv][et][0];

        // ---- pass 1: MAX only; stash src + post-leaky score in LDS ----
        float mm = -INFINITY;
        for (int c = beg; c < end; c += 16) {
            const int e = c + l16;
            float s = -INFINITY;
            if (e < end) {
                const int srci = cs[e];
                s = ssrc8[srci * 8 + r8] + sdv;
                s = (s >= 0.f) ? s : 0.2f * s;
                const int sl = e - beg;
                if (sl < SLOTS) {
                    sld[sl] = s;
                    if (hh == 0) srl[sl] = srci;
                }
            }
            #pragma unroll
            for (int off = 1; off < 16; off <<= 1)
                s = fmaxf(s, __shfl_xor(s, off));
            mm = fmaxf(mm, s);
        }

        // ---- pass 2: predicated 4-wide gather + weighted sum + z ----
        float4 t = make_float4(0.f, 0.f, 0.f, 0.f);
        float z = 0.f;
        for (int e0 = beg; e0 < end; e0 += 4) {
            const int sl = e0 - beg;         // wave-uniform, multiple of 4
            if (sl + 3 < SLOTS) {
                const bool m1 = (e0 + 1 < end);
                const bool m2 = (e0 + 2 < end);
                const bool m3 = (e0 + 3 < end);
                const int4 sv = *(const int4*)&srl[sl];
                const float4 sc = *(const float4*)&sld[sl];
                const int s0 = sv.x;
                const int s1 = m1 ? sv.y : s0;
                const int s2 = m2 ? sv.z : s0;
                const int s3 = m3 ? sv.w : s0;
                const float p0 = __expf(sc.x - mm);
                const float p1 = m1 ? __expf(sc.y - mm) : 0.f;
                const float p2 = m2 ? __expf(sc.z - mm) : 0.f;
                const float p3 = m3 ? __expf(sc.w - mm) : 0.f;
                z += (p0 + p1) + (p2 + p3);
                const ushort4 h0 = *(const ushort4*)&h_ab[(size_t)s0 * HD2 + hoff + c4];
                const ushort4 h1 = *(const ushort4*)&h_ab[(size_t)s1 * HD2 + hoff + c4];
                const ushort4 h2 = *(const ushort4*)&h_ab[(size_t)s2 * HD2 + hoff + c4];
                const ushort4 h3 = *(const ushort4*)&h_ab[(size_t)s3 * HD2 + hoff + c4];
                t.x = fmaf(p0, bf2f(h0.x), t.x); t.y = fmaf(p0, bf2f(h0.y), t.y);
                t.z = fmaf(p0, bf2f(h0.z), t.z); t.w = fmaf(p0, bf2f(h0.w), t.w);
                t.x = fmaf(p1, bf2f(h1.x), t.x); t.y = fmaf(p1, bf2f(h1.y), t.y);
                t.z = fmaf(p1, bf2f(h1.z), t.z); t.w = fmaf(p1, bf2f(h1.w), t.w);
                t.x = fmaf(p2, bf2f(h2.x), t.x); t.y = fmaf(p2, bf2f(h2.y), t.y);
                t.z = fmaf(p2, bf2f(h2.z), t.z); t.w = fmaf(p2, bf2f(h2.w), t.w);
                t.x = fmaf(p3, bf2f(h3.x), t.x); t.y = fmaf(p3, bf2f(h3.y), t.y);
                t.z = fmaf(p3, bf2f(h3.z), t.z); t.w = fmaf(p3, bf2f(h3.w), t.w);
            } else {
                // deep-degree fallback: serial, global recompute (correct for any deg)
                const int eend = (e0 + 4 < end) ? e0 + 4 : end;
                for (int e = e0; e < eend; e++) {
                    const int src = cs[e];
                    float v0 = ssrc8[src * 8 + r8] + sdv;
                    v0 = (v0 >= 0.f) ? v0 : 0.2f * v0;
                    const float p = __expf(v0 - mm);
                    z += p;
                    const ushort4 hv =
                        *(const ushort4*)&h_ab[(size_t)src * HD2 + hoff + c4];
                    t.x = fmaf(p, bf2f(hv.x), t.x);
                    t.y = fmaf(p, bf2f(hv.y), t.y);
                    t.z = fmaf(p, bf2f(hv.z), t.z);
                    t.w = fmaf(p, bf2f(hv.w), t.w);
                }
            }
        }

        const float zz = 1.f / (z + 1e-16f);
        a.x = fmaf(t.x, zz, a.x);
        a.y = fmaf(t.y, zz, a.y);
        a.z = fmaf(t.z, zz, a.z);
        a.w = fmaf(t.w, zz, a.w);
    }

    const float4 bv1 = *(const float4*)&b1[c4];
    const float4 bv2 = *(const float4*)&b2[c4];
    float4 v;
    v.x = a.x + bv1.x + bv2.x;
    v.y = a.y + bv1.y + bv2.y;
    v.z = a.z + bv1.z + bv2.z;
    v.w = a.w + bv1.w + bv2.w;
    if (do_leaky) {
        v.x = (v.x >= 0.f) ? v.x : 0.01f * v.x;
        v.y = (v.y >= 0.f) ? v.y : 0.01f * v.y;
        v.z = (v.z >= 0.f) ? v.z : 0.01f * v.z;
        v.w = (v.w >= 0.f) ? v.w : 0.01f * v.w;
    }
    ushort4 o;
    o.x = f2bf(v.x); o.y = f2bf(v.y); o.z = f2bf(v.z); o.w = f2bf(v.w);
    *(ushort4*)&out_bf[(size_t)node * HD + c4] = o;
}

// ---------- host side ----------
#define N_ROWBLK128 ((N_NODES + 127) / 128)

static void run_layer(const unsigned short* a_bf,
                      const int* rp_a, const int* cs_a,
                      const int* rp_b, const int* cs_b,
                      const float* Wa, const float* Wb,
                      const float* as_a, const float* ad_a,
                      const float* as_b, const float* ad_b,
                      const float* b1, const float* b2,
                      unsigned short* Wt2, unsigned short* h_ab,
                      float* ssrc8, float* sdst8,
                      unsigned short* out_bf, int do_leaky,
                      hipStream_t stream) {
    wt2_kernel<<<HD2, 256, 0, stream>>>(Wa, Wb, Wt2);
    gemm_k256<8, true><<<N_ROWBLK128 * 8, 256, 0, stream>>>(
        a_bf, Wt2, nullptr, h_ab, nullptr,
        as_a, ad_a, as_b, ad_b, ssrc8, sdst8, N_NODES, HD2);
    aggregate_both_kernel<<<(N_NODES + 3) / 4, 256, 0, stream>>>(
        rp_a, cs_a, rp_b, cs_b, h_ab, ssrc8, sdst8,
        b1, b2, out_bf, do_leaky);
}

extern "C" void kernel_launch(void* const* d_in, const int* in_sizes, int n_in,
                              void* d_out, int out_size, void* d_ws, size_t ws_size,
                              hipStream_t stream) {
    const float* x    = (const float*)d_in[0];
    const int*   ei_a = (const int*)d_in[1];
    const int*   ei_b = (const int*)d_in[2];
    const float* W0a = (const float*)d_in[3];
    const float* as0a = (const float*)d_in[4];
    const float* ad0a = (const float*)d_in[5];
    const float* b0a = (const float*)d_in[6];
    const float* W0b = (const float*)d_in[7];
    const float* as0b = (const float*)d_in[8];
    const float* ad0b = (const float*)d_in[9];
    const float* b0b = (const float*)d_in[10];
    const float* W1a = (const float*)d_in[11];
    const float* as1a = (const float*)d_in[12];
    const float* ad1a = (const float*)d_in[13];
    const float* b1a = (const float*)d_in[14];
    const float* W1b = (const float*)d_in[15];
    const float* as1b = (const float*)d_in[16];
    const float* ad1b = (const float*)d_in[17];
    const float* b1b = (const float*)d_in[18];
    const float* Wout = (const float*)d_in[19];
    const float* bout = (const float*)d_in[20];
    float* out = (float*)d_out;

    // workspace carve
    unsigned short* h_ab  = (unsigned short*)d_ws;          // N*512 ushort
    unsigned short* bf_in = h_ab + (size_t)N_NODES * HD2;   // N*256 ushort
    unsigned short* Wt2   = bf_in + (size_t)N_NODES * HD;   // 512*256 ushort
    float* ssrc8  = (float*)(Wt2 + (size_t)HD2 * KDIM);     // N*8
    float* sdst8  = ssrc8 + (size_t)N_NODES * 8;            // N*8
    int*   ibase  = (int*)(sdst8 + (size_t)N_NODES * 8);
    int* deg     = ibase;                  // 2N (concat a|b)
    int* cursor  = deg + 2 * N_NODES;      // 2N
    int* rp_a    = cursor + 2 * N_NODES;   // N+1
    int* cs_a    = rp_a + N_NODES + 1;     // E
    int* rp_b    = cs_a + E_EDGES;         // N+1
    int* cs_b    = rp_b + N_NODES + 1;     // E
    int* excl    = cs_b + E_EDGES;         // 2N
    int* bsums   = excl + 2 * N_NODES;     // 128

    const size_t NF = (size_t)N_NODES * HD;
    const int nf4_blocks = (int)((NF / 4 + 255) / 256);
    const int n2 = 2 * N_NODES;
    const int sb = (n2 + 1023) / 1024;     // 98

    // ---- CSR for both edge types (6 split kernels; r12's coop fusion = 307us) ----
    zero_int_kernel<<<(n2 + 255) / 256, 256, 0, stream>>>(deg, n2);
    hist2_kernel<<<(2 * E_EDGES + 255) / 256, 256, 0, stream>>>(ei_a, ei_b, deg);
    scan_local_kernel<<<sb, 1024, 0, stream>>>(deg, excl, bsums, n2);
    scan_bsums_kernel<<<1, 64, 0, stream>>>(bsums, sb);
    scan_add2_kernel<<<(n2 + 255) / 256, 256, 0, stream>>>(
        excl, bsums, rp_a, rp_b, cursor, n2);
    scatter2_kernel<<<(2 * E_EDGES + 255) / 256, 256, 0, stream>>>(
        ei_a, ei_b, cursor, cs_a, cs_b);

    // ---- layer 0 ----
    convert_bf16_kernel<<<nf4_blocks, 256, 0, stream>>>(x, bf_in, (int)NF);
    run_layer(bf_in, rp_a, cs_a, rp_b, cs_b, W0a, W0b,
              as0a, ad0a, as0b, ad0b, b0a, b0b, Wt2, h_ab,
              ssrc8, sdst8, bf_in, /*leaky=*/1, stream);

    // ---- layer 1 ----
    run_layer(bf_in, rp_a, cs_a, rp_b, cs_b, W1a, W1b,
              as1a, ad1a, as1b, ad1b, b1a, b1b, Wt2, h_ab,
              ssrc8, sdst8, bf_in, /*leaky=*/0, stream);

    // ---- output projection (3 x 64 padded cols covers NC=153) ----
    wt_kernel<<<KDIM, 256, 0, stream>>>(Wout, Wt2, NC);
    gemm_k256<3, false><<<N_ROWBLK128 * 3, 256, 0, stream>>>(
        bf_in, Wt2, out, nullptr, bout,
        nullptr, nullptr, nullptr, nullptr, nullptr, nullptr, N_NODES, NC);
}